// Round 10
// baseline (195.882 us; speedup 1.0000x reference)
//
#include <hip/hip_runtime.h>
#include <hip/hip_cooperative_groups.h>
#include <math.h>

namespace cg = cooperative_groups;

// YOLO loss, 3 scales: G in {13,26,52}, B=32, A=3, 85 ch (5+80), IMG=416.
// Inputs: fm0, yt0, fm1, yt1, fm2, yt2, anchors(9x2). Output: 5 floats.
//
// Hard-won notes (MI355X):
//  - fp atomicAdd on global = CAS loop (~40ns/success serialized). NEVER.
//  - threadfence+ticket per block ~18ns/block at coherence point (R6: +40us).
//  - Grid underfill kills gathers: 96x1024 grid = 8.5% occupancy, 99us (R9).
//  - Dispatch boundary ~6-7us each (R2/R4/R8). 3 dispatches = ~13us overhead.
//  - This round: cooperative single dispatch, 672 blocks x 512 thr (1 thr/cell,
//    65% wave fill, 3 blk/CU co-resident via __launch_bounds__(512,6)).
//    Static per-range compaction (no atomics/init); AGENT loads for cross-XCD.
//    Fallback to 3 plain dispatches if coop launch fails.

constexpr int   NCLS = 80;
constexpr int   CAP  = 20;       // max positives per (s,b) (NOBJ=20)
constexpr float IMGF = 416.0f;

constexpr int NBLK = 672;        // units: s0 32x1, s1 32x4, s2 32x16
constexpr int TPB  = 512;

// ws layout (all rewritten every call; end = 282240 B, same as known-good R7):
constexpr size_t OFF_PART = 0;                         // float4 part[672]
constexpr size_t OFF_CNT  = (size_t)NBLK * 16;         // 10752: int cnt[672]
constexpr size_t OFF_ENT  = OFF_CNT + NBLK * 4;        // 13440: float4 ent[672*20]
constexpr size_t OFF_ENTN = OFF_ENT + (size_t)NBLK * CAP * 16; // 228480: int entn[672*20]

__device__ __forceinline__ int aload_i(const int* p) {
    return __hip_atomic_load(p, __ATOMIC_RELAXED, __HIP_MEMORY_SCOPE_AGENT);
}
__device__ __forceinline__ float aload_f(const float* p) {
    return __hip_atomic_load(p, __ATOMIC_RELAXED, __HIP_MEMORY_SCOPE_AGENT);
}
__device__ inline float sigmoidf_(float x) { return 1.0f / (1.0f + expf(-x)); }
__device__ inline float bcef_(float l, float t) {
    return fmaxf(l, 0.0f) - l * t + log1pf(expf(-fabsf(l)));
}

// unit u -> (scale, batch, range); ranges of 512 cells, a-major cell order.
struct UM { int s, b, r, G, GG, GG3, aoff, NR, ubase; };
__device__ inline UM umap(int u) {
    UM m;
    if (u < 32)       { m.s = 0; m.b = u;  m.r = 0;            m.G = 13; m.NR = 1;  m.ubase = u; }
    else if (u < 160) { int i = u - 32;  m.s = 1; m.b = i >> 2; m.r = i & 3;  m.G = 26; m.NR = 4;  m.ubase = 32 + m.b * 4; }
    else              { int i = u - 160; m.s = 2; m.b = i >> 4; m.r = i & 15; m.G = 52; m.NR = 16; m.ubase = 160 + m.b * 16; }
    m.GG = m.G * m.G; m.GG3 = 3 * m.GG;
    m.aoff = (m.s == 0) ? 6 : (m.s == 1) ? 3 : 0;
    return m;
}

// ---------------- phase 1: collect (one 512-cell range per block) ----------------
__device__ void dev_collect(int bid, int tid,
        const float* __restrict__ yt0, const float* __restrict__ yt1,
        const float* __restrict__ yt2,
        int* __restrict__ cnt, float4* __restrict__ ent, int* __restrict__ entn) {
    UM m = umap(bid);
    const float* yt = (m.s == 0) ? yt0 : (m.s == 1) ? yt1 : yt2;
    int lane = tid & 63, wid = tid >> 6;
    __shared__ int s_wcnt[8];

    int c = m.r * TPB + tid;
    float obj = 0.0f;
    int n = 0;
    if (c < m.GG3) {
        int a = c / m.GG, sp = c - a * m.GG;
        n = sp * 3 + a;
        obj = yt[(size_t)(m.b * m.GG3 + n) * 85 + 4];
    }
    bool pos = obj > 0.5f;
    unsigned long long mask = __ballot(pos);
    if (lane == 0) s_wcnt[wid] = __popcll(mask);
    __syncthreads();
    int wpre = 0, tot = 0;
    #pragma unroll
    for (int w = 0; w < 8; ++w) { int v = s_wcnt[w]; if (w < wid) wpre += v; tot += v; }
    int rank = wpre + (int)__popcll(mask & ((1ull << lane) - 1ull));
    if (pos && rank < CAP) {
        size_t yb = (size_t)(m.b * m.GG3 + n) * 85;
        ent[bid * CAP + rank] = make_float4(yt[yb], yt[yb + 1], yt[yb + 2], yt[yb + 3]);
        entn[bid * CAP + rank] = n;
    }
    if (tid == 0) cnt[bid] = min(tot, CAP);
}

// ---------------- phase 2: pos slots (1/wave) + conf (own 512 cells) ----------------
__device__ void dev_compute(int bid, int tid,
        const float* __restrict__ fm0, const float* __restrict__ fm1,
        const float* __restrict__ fm2,
        const float* __restrict__ yt0, const float* __restrict__ yt1,
        const float* __restrict__ yt2,
        const float* __restrict__ anch,
        const int* __restrict__ cnt, const float4* __restrict__ ent,
        const int* __restrict__ entn, float4* __restrict__ part) {
    int lane = tid & 63, wid = tid >> 6;
    __shared__ int   s_rc[16];
    __shared__ int   s_pref[17];
    __shared__ float s_minx[CAP], s_maxx[CAP], s_miny[CAP], s_maxy[CAP], s_area[CAP];
    __shared__ int   s_tn[CAP];
    __shared__ int   s_total;
    __shared__ float4 s_w[8];

    // ---- stage this unit's (s,b) full target list ----
    UM mu = umap(bid);
    const float* fmu = (mu.s == 0) ? fm0 : (mu.s == 1) ? fm1 : fm2;
    if (tid < mu.NR) s_rc[tid] = aload_i(&cnt[mu.ubase + tid]);
    __syncthreads();
    if (tid == 0) {
        int acc = 0;
        for (int r = 0; r < mu.NR; ++r) { s_pref[r] = acc; acc += s_rc[r]; }
        s_pref[mu.NR] = acc;
        s_total = acc;        // <= 20
    }
    __syncthreads();
    int cn_u = s_total;
    if (tid < cn_u) {
        int r = 0;
        while (r + 1 < mu.NR && s_pref[r + 1] <= tid) ++r;
        int e = (mu.ubase + r) * CAP + (tid - s_pref[r]);
        const float* ep = (const float*)&ent[e];
        float x = aload_f(ep), y = aload_f(ep + 1), w = aload_f(ep + 2), h = aload_f(ep + 3);
        s_minx[tid] = x - w * 0.5f;
        s_maxx[tid] = x + w * 0.5f;
        s_miny[tid] = y - h * 0.5f;
        s_maxy[tid] = y + h * 0.5f;
        s_area[tid] = w * h;
        s_tn[tid]   = aload_i(&entn[e]);
    }
    __syncthreads();

    float ax = 0.f, aw2 = 0.f, ap = 0.f, ac = 0.f;

    // ---- pos slot: one per wave (slot = bid*8 + wid; 3072 slots) ----
    int slot = bid * 8 + wid;
    if (slot < 96 * 32) {
        int sb = slot >> 5, j = slot & 31;
        int ss = sb >> 5, bb = sb & 31;
        const float *fm, *yt;
        int G, aoff, NR, ubase;
        if (ss == 0)      { fm = fm0; yt = yt0; G = 13; aoff = 6; NR = 1;  ubase = bb; }
        else if (ss == 1) { fm = fm1; yt = yt1; G = 26; aoff = 3; NR = 4;  ubase = 32 + bb * 4; }
        else              { fm = fm2; yt = yt2; G = 52; aoff = 0; NR = 16; ubase = 160 + bb * 16; }
        int GG = G * G, GG3 = 3 * GG;
        float stridef = IMGF / (float)G;
        int cr = (lane < NR) ? aload_i(&cnt[ubase + lane]) : 0;
        int incl = cr;
        for (int d = 1; d < 64; d <<= 1) {
            int v = __shfl_up(incl, d);
            if (lane >= d) incl += v;
        }
        int excl = incl - cr;
        bool mine = (j >= excl) && (j < incl);
        unsigned long long msk = __ballot(mine);
        if (msk != 0ull) {
            int rs = __ffsll((unsigned long long)msk) - 1;
            int excl_s = __shfl(excl, rs);
            int e = (ubase + rs) * CAP + (j - excl_s);
            const float* ep = (const float*)&ent[e];
            float4 tb = make_float4(aload_f(ep), aload_f(ep + 1), aload_f(ep + 2), aload_f(ep + 3));
            int n = aload_i(&entn[e]);
            int a = n % 3, sp = n / 3;
            int jj = sp % G, ii = sp / G;
            int ybase = (bb * GG3 + n) * 85;
            int fbase = (bb * 255 + a * 85) * GG + sp;
            for (int cc = lane; cc < NCLS; cc += 64) {
                float pl  = fm[fbase + (5 + cc) * GG];
                float tl  = yt[ybase + 5 + cc];
                float lab = 0.99f * tl + 1.25e-4f;    // (1-delta)*t + delta/NC
                ap += bcef_(pl, lab);
            }
            if (lane == 0) {
                float p0 = fm[fbase];
                float p1 = fm[fbase + GG];
                float p2 = fm[fbase + 2 * GG];
                float p3 = fm[fbase + 3 * GG];
                float bcx = (sigmoidf_(p0) + (float)jj) * stridef;
                float bcy = (sigmoidf_(p1) + (float)ii) * stridef;
                float predx = bcx / stridef - (float)jj;
                float predy = bcy / stridef - (float)ii;
                float truex = tb.x / stridef - (float)jj;
                float truey = tb.y / stridef - (float)ii;
                float dx = truex - predx, dy = truey - predy;
                float bscale = 2.0f - (tb.z / IMGF) * (tb.w / IMGF);
                float aw = anch[(aoff + a) * 2], ah = anch[(aoff + a) * 2 + 1];
                float pw = expf(p2) * (aw / stridef) * stridef;
                float ph = expf(p3) * (ah / stridef) * stridef;
                float ptw = pw / aw, pth = ph / ah;
                float ttw = tb.z / aw, tth = tb.w / ah;
                ttw = (ttw == 0.0f) ? 1.0f : ttw;
                tth = (tth == 0.0f) ? 1.0f : tth;
                ptw = (ptw == 0.0f) ? 1.0f : ptw;
                pth = (pth == 0.0f) ? 1.0f : pth;
                ttw = logf(fminf(fmaxf(ttw, 1e-9f), 1e9f));
                tth = logf(fminf(fmaxf(tth, 1e-9f), 1e9f));
                ptw = logf(fminf(fmaxf(ptw, 1e-9f), 1e9f));
                pth = logf(fminf(fmaxf(pth, 1e-9f), 1e9f));
                float dw = ttw - ptw, dh = tth - pth;
                ax  += (dx * dx + dy * dy) * bscale;
                aw2 += (dw * dw + dh * dh) * bscale;
            }
        }
    }

    // ---- conf for this unit's 512 cells ----
    {
        int c = mu.r * TPB + tid;
        if (c < mu.GG3) {
            float stridef = IMGF / (float)mu.G;
            int a = c / mu.GG, sp = c - a * mu.GG;
            int n = sp * 3 + a;
            int jj = sp % mu.G, ii = sp / mu.G;
            int fbase = (mu.b * 255 + a * 85) * mu.GG + sp;
            float p0 = fmu[fbase];
            float p1 = fmu[fbase + mu.GG];
            float p2 = fmu[fbase + 2 * mu.GG];
            float p3 = fmu[fbase + 3 * mu.GG];
            float p4 = fmu[fbase + 4 * mu.GG];
            float aw = anch[(mu.aoff + a) * 2], ah = anch[(mu.aoff + a) * 2 + 1];
            float cx = (sigmoidf_(p0) + (float)jj) * stridef;
            float cy = (sigmoidf_(p1) + (float)ii) * stridef;
            float pw = expf(p2) * (aw / stridef) * stridef;
            float ph = expf(p3) * (ah / stridef) * stridef;
            float pminx = cx - pw * 0.5f, pmaxx = cx + pw * 0.5f;
            float pminy = cy - ph * 0.5f, pmaxy = cy + ph * 0.5f;
            float parea = pw * ph;
            float best = 0.0f, mfl = 0.0f;
            for (int k = 0; k < cn_u; ++k) {
                if (s_tn[k] == n) mfl = 1.0f;
                float iw = fminf(pmaxx, s_maxx[k]) - fmaxf(pminx, s_minx[k]);
                float ih = fminf(pmaxy, s_maxy[k]) - fmaxf(pminy, s_miny[k]);
                iw = fmaxf(iw, 0.0f);
                ih = fmaxf(ih, 0.0f);
                float inter = iw * ih;
                float iou = inter / ((parea + s_area[k] - inter) + 1e-10f);
                best = fmaxf(best, iou);
            }
            float ign = (cn_u > 0 && best < 0.5f) ? 1.0f : 0.0f;
            float bce = bcef_(p4, mfl);
            float d = fabsf(mfl - sigmoidf_(p4));
            ac = (mfl * bce + 0.5f * (1.0f - mfl) * ign * bce) * (d * d);
        }
    }

    // ---- block reduce; plain part store ----
    for (int off = 32; off; off >>= 1) {
        ax  += __shfl_down(ax,  off);
        aw2 += __shfl_down(aw2, off);
        ap  += __shfl_down(ap,  off);
        ac  += __shfl_down(ac,  off);
    }
    if (lane == 0) s_w[wid] = make_float4(ax, aw2, ap, ac);
    __syncthreads();
    if (tid == 0) {
        float X = 0.f, W = 0.f, P = 0.f, C = 0.f;
        #pragma unroll
        for (int w = 0; w < 8; ++w) { X += s_w[w].x; W += s_w[w].y; P += s_w[w].z; C += s_w[w].w; }
        part[bid] = make_float4(X, W, P, C);
    }
}

// ---------------- phase 3: final reduce ----------------
__device__ void dev_reduce(int tid, const float4* __restrict__ part,
                           float* __restrict__ out) {
    double x = 0.0, w = 0.0, p = 0.0, c = 0.0;
    for (int i = tid; i < NBLK; i += TPB) {
        const float* pp = (const float*)&part[i];
        x += (double)aload_f(pp);
        w += (double)aload_f(pp + 1);
        p += (double)aload_f(pp + 2);
        c += (double)aload_f(pp + 3);
    }
    for (int off = 32; off; off >>= 1) {
        x += __shfl_down(x, off);
        w += __shfl_down(w, off);
        p += __shfl_down(p, off);
        c += __shfl_down(c, off);
    }
    __shared__ double sd[8][4];
    int wid = tid >> 6, lane = tid & 63;
    if (lane == 0) { sd[wid][0] = x; sd[wid][1] = w; sd[wid][2] = p; sd[wid][3] = c; }
    __syncthreads();
    if (tid == 0) {
        double X = 0, W = 0, P = 0, C = 0;
        for (int i = 0; i < 8; ++i) { X += sd[i][0]; W += sd[i][1]; P += sd[i][2]; C += sd[i][3]; }
        double xy = 5.0 * X / 32.0;
        double wh = 5.0 * W / 32.0;
        double cf = C / 32.0;
        double pb = P / 32.0;
        out[0] = (float)(xy + wh + cf + pb);
        out[1] = (float)xy;
        out[2] = (float)wh;
        out[3] = (float)cf;
        out[4] = (float)pb;
    }
}

// ---------------- cooperative single-dispatch kernel ----------------
__global__ __launch_bounds__(TPB, 6) void k_coop(
        const float* fm0, const float* fm1, const float* fm2,
        const float* yt0, const float* yt1, const float* yt2,
        const float* anch,
        int* cnt, float4* ent, int* entn, float4* part, float* out) {
    int bid = blockIdx.x, tid = threadIdx.x;
    cg::grid_group g = cg::this_grid();
    dev_collect(bid, tid, yt0, yt1, yt2, cnt, ent, entn);
    g.sync();
    dev_compute(bid, tid, fm0, fm1, fm2, yt0, yt1, yt2, anch, cnt, ent, entn, part);
    g.sync();
    if (bid == 0) dev_reduce(tid, part, out);
}

// ---------------- fallback: same phases as 3 plain dispatches ----------------
__global__ __launch_bounds__(TPB, 6) void k_p1(
        const float* yt0, const float* yt1, const float* yt2,
        int* cnt, float4* ent, int* entn) {
    dev_collect(blockIdx.x, threadIdx.x, yt0, yt1, yt2, cnt, ent, entn);
}
__global__ __launch_bounds__(TPB, 6) void k_p2(
        const float* fm0, const float* fm1, const float* fm2,
        const float* yt0, const float* yt1, const float* yt2,
        const float* anch, const int* cnt, const float4* ent, const int* entn,
        float4* part) {
    dev_compute(blockIdx.x, threadIdx.x, fm0, fm1, fm2, yt0, yt1, yt2, anch,
                cnt, ent, entn, part);
}
__global__ __launch_bounds__(TPB) void k_p3(const float4* part, float* out) {
    dev_reduce(threadIdx.x, part, out);
}

extern "C" void kernel_launch(void* const* d_in, const int* in_sizes, int n_in,
                              void* d_out, int out_size, void* d_ws, size_t ws_size,
                              hipStream_t stream) {
    const float* fm0  = (const float*)d_in[0];
    const float* yt0  = (const float*)d_in[1];
    const float* fm1  = (const float*)d_in[2];
    const float* yt1  = (const float*)d_in[3];
    const float* fm2  = (const float*)d_in[4];
    const float* yt2  = (const float*)d_in[5];
    const float* anch = (const float*)d_in[6];
    float* out = (float*)d_out;

    char* ws = (char*)d_ws;
    float4* part = (float4*)(ws + OFF_PART);
    int*    cnt  = (int*)(ws + OFF_CNT);
    float4* ent  = (float4*)(ws + OFF_ENT);
    int*    entn = (int*)(ws + OFF_ENTN);

    void* args[] = { (void*)&fm0, (void*)&fm1, (void*)&fm2,
                     (void*)&yt0, (void*)&yt1, (void*)&yt2, (void*)&anch,
                     (void*)&cnt, (void*)&ent, (void*)&entn,
                     (void*)&part, (void*)&out };
    hipError_t err = hipLaunchCooperativeKernel((const void*)k_coop,
                                                dim3(NBLK), dim3(TPB),
                                                args, 0, stream);
    if (err != hipSuccess) {
        (void)hipGetLastError();   // clear sticky error; use plain 3-dispatch path
        k_p1<<<NBLK, TPB, 0, stream>>>(yt0, yt1, yt2, cnt, ent, entn);
        k_p2<<<NBLK, TPB, 0, stream>>>(fm0, fm1, fm2, yt0, yt1, yt2, anch,
                                       cnt, ent, entn, part);
        k_p3<<<1, TPB, 0, stream>>>(part, out);
    }
}

// Round 11
// 35.176 us; speedup vs baseline: 5.5687x; 5.5687x over previous
//
#include <hip/hip_runtime.h>
#include <math.h>

// YOLO loss, 3 scales: G in {13,26,52}, B=32, A=3, 85 ch (5+80), IMG=416.
// Inputs: fm0, yt0, fm1, yt1, fm2, yt2, anchors(9x2). Output: 5 floats.
//
// Hard-won notes (MI355X):
//  - fp atomicAdd on global = CAS loop. NEVER (R0/R3).
//  - threadfence+ticket per block ~18ns/block at coherence point (R6: +40us).
//  - cooperative grid.sync() ~85us EACH on gfx950 (R10: 185us kernel). Never.
//  - Intra-kernel spin barriers need co-residency caps -> TLP starvation (R5).
//  - Per-CU memory throughput ~10B/cy (~25GB/s): a block's byte footprint
//    must stay <~100KB or it becomes a multi-us serial tail (R9: one block
//    scanning 519KB = ~21us -> 99us kernel). Spread bytes across blocks.
//  - Dispatch boundary ~5-7us each (R2/R4/R8). 3 dispatches = best so far.
//  - ZERO atomics, ZERO fences. Deterministic ballot compaction.

constexpr int   NCLS = 80;
constexpr int   PMAX = 8;      // sub-lists per (s,b): s0:1, s1:2, s2:8
constexpr int   CAP  = 20;     // per sub-list; total positives per (s,b) <= 20
constexpr float IMGF = 416.0f;

constexpr int NBLK_COLLECT = 32 * (1 + 2 + 8);   // 352
constexpr int NBLK_CONF    = 96 + 288 + 1056;    // 1440
constexpr int NPART        = NBLK_COLLECT + NBLK_CONF;  // 1792

// ws layout (all consumed bytes rewritten every call):
constexpr size_t OFF_PART = 0;                                    // float4 part[1792]
constexpr size_t OFF_CNT  = (size_t)NPART * 16;                   // 28672: int cnt[96*8]
constexpr size_t OFF_ENT  = OFF_CNT + 96 * PMAX * 4;              // 31744: float4 ent[96*8*20]
constexpr size_t OFF_ENTN = OFF_ENT + (size_t)96 * PMAX * CAP * 16; // 277504: int entn[96*8*20]
// end = 338944 bytes

__device__ inline float sigmoidf_(float x) { return 1.0f / (1.0f + expf(-x)); }
__device__ inline float bcef_(float l, float t) {
    return fmaxf(l, 0.0f) - l * t + log1pf(expf(-fabsf(l)));
}

// One block per (scale, b, range): ballot-compact positives (plain stores),
// then pos losses for the block's own entries (one per wave).
__global__ __launch_bounds__(512) void k_collect(
        const float* __restrict__ fm0, const float* __restrict__ fm1,
        const float* __restrict__ fm2,
        const float* __restrict__ yt0, const float* __restrict__ yt1,
        const float* __restrict__ yt2,
        const float* __restrict__ anch,
        int* __restrict__ cnt, float4* __restrict__ ent, int* __restrict__ entn,
        float4* __restrict__ part) {
    int bid = blockIdx.x, tid = threadIdx.x;
    int lane = tid & 63, wid = tid >> 6;
    int s, b, p, NR, G, aoff;
    const float *yt, *fm;
    if (bid < 32)      { s = 0; b = bid;          p = 0;       NR = 1; G = 13; yt = yt0; fm = fm0; aoff = 6; }
    else if (bid < 96) { int i = bid - 32; s = 1; b = i >> 1; p = i & 1; NR = 2; G = 26; yt = yt1; fm = fm1; aoff = 3; }
    else               { int i = bid - 96; s = 2; b = i >> 3; p = i & 7; NR = 8; G = 52; yt = yt2; fm = fm2; aoff = 0; }
    int GG  = G * G, GG3 = 3 * GG;
    int per = (GG3 + NR - 1) / NR;           // 507 / 1014 / 1014
    int nbase = p * per;
    int count = min(per, GG3 - nbase);
    int nit = (count + 511) / 512;           // 1 or 2
    int sb = s * 32 + b;
    float stridef = IMGF / (float)G;

    __shared__ int    s_wcnt[8];
    __shared__ int    s_base;
    __shared__ int    s_n[CAP];
    __shared__ float4 s_box[CAP];
    __shared__ float4 s_w[8];
    if (tid == 0) s_base = 0;

    float obj[2];
    int   nn[2];
    #pragma unroll
    for (int it = 0; it < 2; ++it) {         // prefetch both rounds
        int c = it * 512 + tid;
        nn[it]  = nbase + c;
        obj[it] = 0.0f;
        if (c < count) obj[it] = yt[(size_t)(b * GG3 + nn[it]) * 85 + 4];
    }
    __syncthreads();

    for (int it = 0; it < nit; ++it) {
        bool pos = obj[it] > 0.5f;
        unsigned long long mask = __ballot(pos);
        if (lane == 0) s_wcnt[wid] = __popcll(mask);
        __syncthreads();
        int wpre = 0, tot = 0;
        #pragma unroll
        for (int w = 0; w < 8; ++w) { int v = s_wcnt[w]; if (w < wid) wpre += v; tot += v; }
        int rank = s_base + wpre + (int)__popcll(mask & ((1ull << lane) - 1ull));
        if (pos && rank < CAP) {
            size_t yb = (size_t)(b * GG3 + nn[it]) * 85;
            float4 box = make_float4(yt[yb], yt[yb + 1], yt[yb + 2], yt[yb + 3]);
            int e = (sb * PMAX + p) * CAP + rank;
            ent[e]  = box;
            entn[e] = nn[it];
            s_box[rank] = box;
            s_n[rank]   = nn[it];
        }
        __syncthreads();
        if (tid == 0) s_base += tot;
        __syncthreads();
    }
    int cn = min(s_base, CAP);
    if (tid == 0) {
        cnt[sb * PMAX + p] = cn;
        if (p == 0)                          // zero unused sub-list counts
            for (int q = NR; q < PMAX; ++q) cnt[sb * PMAX + q] = 0;
    }

    // ---- pos losses for this block's entries: one per wave ----
    float ax = 0.f, aw2 = 0.f, ap = 0.f;
    for (int slot = wid; slot < cn; slot += 8) {
        float4 tb = s_box[slot];
        int n  = s_n[slot];
        int a  = n % 3;
        int sp = n / 3;
        int jj = sp % G, ii = sp / G;
        int ybase = (b * GG3 + n) * 85;
        int fbase = (b * 255 + a * 85) * GG + sp;
        for (int c = lane; c < NCLS; c += 64) {       // class BCE, lane-parallel
            float pl  = fm[fbase + (5 + c) * GG];
            float tl  = yt[ybase + 5 + c];
            float lab = 0.99f * tl + 1.25e-4f;        // (1-delta)*t + delta/NC
            ap += bcef_(pl, lab);
        }
        if (lane == 0) {
            float p0 = fm[fbase];
            float p1 = fm[fbase + GG];
            float p2 = fm[fbase + 2 * GG];
            float p3 = fm[fbase + 3 * GG];
            float bcx = (sigmoidf_(p0) + (float)jj) * stridef;
            float bcy = (sigmoidf_(p1) + (float)ii) * stridef;
            float predx = bcx / stridef - (float)jj;
            float predy = bcy / stridef - (float)ii;
            float truex = tb.x / stridef - (float)jj;
            float truey = tb.y / stridef - (float)ii;
            float dx = truex - predx, dy = truey - predy;
            float bscale = 2.0f - (tb.z / IMGF) * (tb.w / IMGF);
            float aw = anch[(aoff + a) * 2], ah = anch[(aoff + a) * 2 + 1];
            float pw = expf(p2) * (aw / stridef) * stridef;
            float ph = expf(p3) * (ah / stridef) * stridef;
            float ptw = pw / aw, pth = ph / ah;
            float ttw = tb.z / aw, tth = tb.w / ah;
            ttw = (ttw == 0.0f) ? 1.0f : ttw;
            tth = (tth == 0.0f) ? 1.0f : tth;
            ptw = (ptw == 0.0f) ? 1.0f : ptw;
            pth = (pth == 0.0f) ? 1.0f : pth;
            ttw = logf(fminf(fmaxf(ttw, 1e-9f), 1e9f));
            tth = logf(fminf(fmaxf(tth, 1e-9f), 1e9f));
            ptw = logf(fminf(fmaxf(ptw, 1e-9f), 1e9f));
            pth = logf(fminf(fmaxf(pth, 1e-9f), 1e9f));
            float dw = ttw - ptw, dh = tth - pth;
            ax  += (dx * dx + dy * dy) * bscale;
            aw2 += (dw * dw + dh * dh) * bscale;
        }
    }
    for (int off = 32; off; off >>= 1) {
        ax  += __shfl_down(ax,  off);
        aw2 += __shfl_down(aw2, off);
        ap  += __shfl_down(ap,  off);
    }
    if (lane == 0) s_w[wid] = make_float4(ax, aw2, ap, 0.f);
    __syncthreads();
    if (tid == 0) {
        float X = 0.f, W = 0.f, P = 0.f;
        #pragma unroll
        for (int w = 0; w < 8; ++w) { X += s_w[w].x; W += s_w[w].y; P += s_w[w].z; }
        part[bid] = make_float4(X, W, P, 0.f);
    }
}

// Conf loss: 1440 blocks x 256; 256 cells of one (scale,b,a) chunk each.
// Stages exactly the (s,b)'s <=20 targets (count-then-gather).
__global__ __launch_bounds__(256) void k_conf(
        const float* __restrict__ fm0, const float* __restrict__ fm1,
        const float* __restrict__ fm2,
        const float* __restrict__ anch,
        const int* __restrict__ cnt, const float4* __restrict__ ent,
        const int* __restrict__ entn, float4* __restrict__ part) {
    __shared__ int   s_cnt8[8];
    __shared__ int   s_pref[9];
    __shared__ float s_minx[32], s_maxx[32], s_miny[32], s_maxy[32], s_area[32];
    __shared__ int   s_tn[32];
    __shared__ float s_w1[4];

    int bid = blockIdx.x;
    int tid = threadIdx.x;
    int wid = tid >> 6, lane = tid & 63;

    int cb = bid;
    const float *fm;
    int G, chunks, s, aoff;
    if (cb < 96)       { fm = fm0; G = 13; chunks = 1;  s = 0; aoff = 6; }
    else if (cb < 384) { cb -= 96;  fm = fm1; G = 26; chunks = 3;  s = 1; aoff = 3; }
    else               { cb -= 384; fm = fm2; G = 52; chunks = 11; s = 2; aoff = 0; }
    int chunk = cb % chunks;
    int ba    = cb / chunks;
    int b = ba / 3, a = ba % 3;
    int GG = G * G;
    float stridef = IMGF / (float)G;
    int sb = s * 32 + b;

    if (tid < 8) s_cnt8[tid] = cnt[sb * PMAX + tid];
    __syncthreads();
    if (tid == 0) {
        int acc = 0;
        #pragma unroll
        for (int q = 0; q < 8; ++q) { s_pref[q] = acc; acc += s_cnt8[q]; }
        s_pref[8] = min(acc, 32);
    }
    __syncthreads();
    int total = s_pref[8];
    if (tid < total) {                     // gather exactly the real entries
        int q = 0;
        while (q < 7 && tid >= s_pref[q + 1]) ++q;
        int e = (sb * PMAX + q) * CAP + (tid - s_pref[q]);
        float4 tb = ent[e];
        s_minx[tid] = tb.x - tb.z * 0.5f;
        s_maxx[tid] = tb.x + tb.z * 0.5f;
        s_miny[tid] = tb.y - tb.w * 0.5f;
        s_maxy[tid] = tb.y + tb.w * 0.5f;
        s_area[tid] = tb.z * tb.w;
        s_tn[tid]   = entn[e];
    }
    __syncthreads();

    float ac = 0.f;
    int sp = chunk * 256 + tid;
    if (sp < GG) {
        int jj = sp % G, ii = sp / G;
        int n = sp * 3 + a;
        int fbase = (b * 255 + a * 85) * GG + sp;
        float p0 = fm[fbase];
        float p1 = fm[fbase + GG];
        float p2 = fm[fbase + 2 * GG];
        float p3 = fm[fbase + 3 * GG];
        float p4 = fm[fbase + 4 * GG];
        float aw = anch[(aoff + a) * 2], ah = anch[(aoff + a) * 2 + 1];
        float cx = (sigmoidf_(p0) + (float)jj) * stridef;
        float cy = (sigmoidf_(p1) + (float)ii) * stridef;
        float pw = expf(p2) * (aw / stridef) * stridef;
        float ph = expf(p3) * (ah / stridef) * stridef;
        float pminx = cx - pw * 0.5f, pmaxx = cx + pw * 0.5f;
        float pminy = cy - ph * 0.5f, pmaxy = cy + ph * 0.5f;
        float parea = pw * ph;
        float best = 0.0f, m = 0.0f;
        for (int k = 0; k < total; ++k) {
            if (s_tn[k] == n) m = 1.0f;
            float iw = fminf(pmaxx, s_maxx[k]) - fmaxf(pminx, s_minx[k]);
            float ih = fminf(pmaxy, s_maxy[k]) - fmaxf(pminy, s_miny[k]);
            iw = fmaxf(iw, 0.0f);
            ih = fmaxf(ih, 0.0f);
            float inter = iw * ih;
            float iou = inter / ((parea + s_area[k] - inter) + 1e-10f);
            best = fmaxf(best, iou);
        }
        float ign = (total > 0 && best < 0.5f) ? 1.0f : 0.0f;
        float bce = bcef_(p4, m);
        float d = fabsf(m - sigmoidf_(p4));
        ac = (m * bce + 0.5f * (1.0f - m) * ign * bce) * (d * d);
    }

    for (int off = 32; off; off >>= 1) ac += __shfl_down(ac, off);
    if (lane == 0) s_w1[wid] = ac;
    __syncthreads();
    if (tid == 0)
        part[NBLK_COLLECT + bid] =
            make_float4(0.f, 0.f, 0.f, s_w1[0] + s_w1[1] + s_w1[2] + s_w1[3]);
}

// Sum the 1792 per-block partials (fixed order, double accumulation) -> out[5].
__global__ __launch_bounds__(512) void k_reduce(
        const float4* __restrict__ part, float* __restrict__ out) {
    int t = threadIdx.x;
    double x = 0.0, w = 0.0, p = 0.0, c = 0.0;
    for (int i = t; i < NPART; i += 512) {
        float4 v = part[i];
        x += (double)v.x; w += (double)v.y; p += (double)v.z; c += (double)v.w;
    }
    for (int off = 32; off; off >>= 1) {
        x += __shfl_down(x, off);
        w += __shfl_down(w, off);
        p += __shfl_down(p, off);
        c += __shfl_down(c, off);
    }
    __shared__ double sx[8], sw[8], sp[8], sc[8];
    int wid = t >> 6, lane = t & 63;
    if (lane == 0) { sx[wid] = x; sw[wid] = w; sp[wid] = p; sc[wid] = c; }
    __syncthreads();
    if (t == 0) {
        double X = 0, W = 0, P = 0, C = 0;
        for (int i = 0; i < 8; ++i) { X += sx[i]; W += sw[i]; P += sp[i]; C += sc[i]; }
        double xy = 5.0 * X / 32.0;
        double wh = 5.0 * W / 32.0;
        double cf = C / 32.0;
        double pb = P / 32.0;
        out[0] = (float)(xy + wh + cf + pb);
        out[1] = (float)xy;
        out[2] = (float)wh;
        out[3] = (float)cf;
        out[4] = (float)pb;
    }
}

extern "C" void kernel_launch(void* const* d_in, const int* in_sizes, int n_in,
                              void* d_out, int out_size, void* d_ws, size_t ws_size,
                              hipStream_t stream) {
    const float* fm0  = (const float*)d_in[0];
    const float* yt0  = (const float*)d_in[1];
    const float* fm1  = (const float*)d_in[2];
    const float* yt1  = (const float*)d_in[3];
    const float* fm2  = (const float*)d_in[4];
    const float* yt2  = (const float*)d_in[5];
    const float* anch = (const float*)d_in[6];
    float* out = (float*)d_out;

    char* ws = (char*)d_ws;
    float4* part = (float4*)(ws + OFF_PART);
    int*    cnt  = (int*)(ws + OFF_CNT);
    float4* ent  = (float4*)(ws + OFF_ENT);
    int*    entn = (int*)(ws + OFF_ENTN);

    k_collect<<<NBLK_COLLECT, 512, 0, stream>>>(
        fm0, fm1, fm2, yt0, yt1, yt2, anch, cnt, ent, entn, part);
    k_conf<<<NBLK_CONF, 256, 0, stream>>>(
        fm0, fm1, fm2, anch, cnt, ent, entn, part);
    k_reduce<<<1, 512, 0, stream>>>(part, out);
}